// Round 6
// baseline (265.005 us; speedup 1.0000x reference)
//
#include <hip/hip_runtime.h>

#define N_NODES 50000
#define N_EDGES 600000
#define N_GRAPHS 500
#define F 128

typedef short bf16x8 __attribute__((ext_vector_type(8)));
typedef float f32x4 __attribute__((ext_vector_type(4)));
union U4H8 { uint4 u; bf16x8 h; };

// ---- bf16 helpers (RNE) ----
__device__ inline unsigned pk_bf16(float a, float b) {
    unsigned ua = __float_as_uint(a), ub = __float_as_uint(b);
    ua = (ua + 0x7fffu + ((ua >> 16) & 1u)) >> 16;
    ub = (ub + 0x7fffu + ((ub >> 16) & 1u)) >> 16;
    return ua | (ub << 16);
}
__device__ inline float bf16_rnd(float x) {
    unsigned u = __float_as_uint(x);
    u = (u + 0x7fffu + ((u >> 16) & 1u)) & 0xffff0000u;
    return __uint_as_float(u);
}
__device__ inline unsigned short bf16_1(float a) {
    unsigned ua = __float_as_uint(a);
    return (unsigned short)((ua + 0x7fffu + ((ua >> 16) & 1u)) >> 16);
}
#define BF_LO(u) __uint_as_float((u) << 16)
#define BF_HI(u) __uint_as_float((u) & 0xffff0000u)

#define G_CVT  3125
#define G_HIST 2344
#define G_PREPW 24
#define G_BND  196

// ====== merged prep: x->bf16 | dst histogram (saves rank!) | W split-pack | pool bounds ======
__global__ __launch_bounds__(256) void k_prep(const float* __restrict__ x, unsigned short* __restrict__ xb,
                                              const int* __restrict__ dst, int* __restrict__ cnt,
                                              int* __restrict__ rnk,
                                              const float* __restrict__ W1, const float* __restrict__ W2,
                                              const float* __restrict__ W3,
                                              uint4* __restrict__ Whi, uint4* __restrict__ Wlo,
                                              const int* __restrict__ batch, int* __restrict__ gs) {
    int b = blockIdx.x, tid = threadIdx.x;
    if (b < G_CVT) {
        int idx = b * 256 + tid;
        if (idx < N_NODES * F / 8) {
            const float4* xr = (const float4*)(x + (size_t)idx * 8);
            float4 a = xr[0], c = xr[1];
            uint4 o;
            o.x = pk_bf16(a.x, a.y); o.y = pk_bf16(a.z, a.w);
            o.z = pk_bf16(c.x, c.y); o.w = pk_bf16(c.z, c.w);
            ((uint4*)xb)[idx] = o;
        }
    } else if (b < G_CVT + G_HIST) {
        int e = (b - G_CVT) * 256 + tid;
        // rank doubles as the CSR placement slot -> k_fill needs NO atomics (r4 lesson:
        // the hist atomic already computes placement; don't pay for it twice)
        if (e < N_EDGES) rnk[e] = atomicAdd(&cnt[dst[e]], 1);
    } else if (b < G_CVT + G_HIST + G_PREPW) {
        int idx = (b - G_CVT - G_HIST) * 256 + tid;   // 0..6143
        int layer = idx >> 11;
        const float* W = (layer == 0) ? W1 : (layer == 1) ? W2 : W3;
        int t = idx & 2047;
        int lane = t & 63, sc = t >> 6;
        int s = sc >> 3, c = sc & 7;
        int q = lane >> 4, m = lane & 15;
        int k0 = 32 * s + 8 * q, n0 = 16 * c + m;
        float w[8], h[8];
        #pragma unroll
        for (int j = 0; j < 8; ++j) {
            w[j] = W[(k0 + j) * F + n0];
            h[j] = bf16_rnd(w[j]);
        }
        uint4 uh, ul;
        uh.x = pk_bf16(h[0], h[1]); uh.y = pk_bf16(h[2], h[3]);
        uh.z = pk_bf16(h[4], h[5]); uh.w = pk_bf16(h[6], h[7]);
        ul.x = pk_bf16(w[0] - h[0], w[1] - h[1]); ul.y = pk_bf16(w[2] - h[2], w[3] - h[3]);
        ul.z = pk_bf16(w[4] - h[4], w[5] - h[5]); ul.w = pk_bf16(w[6] - h[6], w[7] - h[7]);
        Whi[idx] = uh;
        Wlo[idx] = ul;
    } else {
        int i = (b - G_CVT - G_HIST - G_PREPW) * 256 + tid;
        if (i < N_NODES) {
            int bi = batch[i];
            if (i == 0) {
                for (int g = 0; g <= bi; ++g) gs[g] = 0;
            } else {
                int bp = batch[i - 1];
                for (int g = bp + 1; g <= bi; ++g) gs[g] = i;
            }
            if (i == N_NODES - 1) {
                for (int g = bi + 1; g <= N_GRAPHS; ++g) gs[g] = N_NODES;
            }
        }
    }
}

// ================= CSR scan + fill + degree-sort =================
__global__ __launch_bounds__(256) void k_scan1(const int* __restrict__ cnt, int* __restrict__ row_ptr,
                                               int* __restrict__ blksums, float* __restrict__ dinv,
                                               int* __restrict__ dh, int n) {
    __shared__ int s[256];
    __shared__ int dhl[64];
    int tid = threadIdx.x;
    int i = blockIdx.x * 256 + tid;
    if (tid < 64) dhl[tid] = 0;
    int v = (i < n) ? cnt[i] : 0;
    if (i < n) dinv[i] = rsqrtf((float)(v + 1));
    s[tid] = v;
    __syncthreads();
    if (i < n) atomicAdd(&dhl[v < 63 ? v : 63], 1);
    for (int off = 1; off < 256; off <<= 1) {
        int t = (tid >= off) ? s[tid - off] : 0;
        __syncthreads();
        s[tid] += t;
        __syncthreads();
    }
    if (i < n) row_ptr[i] = s[tid] - v;
    if (tid == 255) blksums[blockIdx.x] = s[255];
    __syncthreads();
    if (tid < 64 && dhl[tid] > 0) atomicAdd(&dh[tid], dhl[tid]);
}

__global__ __launch_bounds__(256) void k_scan23(int* __restrict__ row_ptr, const int* __restrict__ blksums,
                                                const int* __restrict__ dh, int* __restrict__ dhoff,
                                                int* __restrict__ dcur, int n, int ne) {
    __shared__ int s[256];
    int tid = threadIdx.x;
    s[tid] = (tid < (int)blockIdx.x) ? blksums[tid] : 0;
    __syncthreads();
    for (int off = 128; off > 0; off >>= 1) {
        if (tid < off) s[tid] += s[tid + off];
        __syncthreads();
    }
    int base = s[0];
    int i = blockIdx.x * 256 + tid;
    if (i < n) row_ptr[i] += base;
    if (i == 0) row_ptr[n] = ne;
    if (blockIdx.x == 0 && tid < 64) {
        int v = dh[tid];
        int x = v;
        #pragma unroll
        for (int off = 1; off < 64; off <<= 1) {
            int t = __shfl_up(x, off, 64);
            if (tid >= off) x += t;
        }
        dhoff[tid] = x - v;   // exclusive prefix
        dcur[tid] = 0;
    }
}

#define G_FILL 2344
#define G_PLACE 196
// fill: ATOMIC-FREE CSR scatter (pos = row_ptr[dst] + saved hist rank; 4B records);
// placement: block-aggregated degree-sort (one global atomic per (block,bin))
__global__ __launch_bounds__(256) void k_fill(const int* __restrict__ src, const int* __restrict__ dst,
                                              const int* __restrict__ row_ptr, const int* __restrict__ rnk,
                                              int* __restrict__ esrc,
                                              const int* __restrict__ dhoff, int* __restrict__ dcur,
                                              int* __restrict__ perm, int ne) {
    __shared__ int lh[64];
    __shared__ int lbase[64];
    int b = blockIdx.x, tid = threadIdx.x;
    if (b < G_FILL) {
        int e = b * 256 + tid;
        if (e < ne) {
            int d = dst[e];
            esrc[row_ptr[d] + rnk[e]] = src[e];
        }
    } else {
        int i = (b - G_FILL) * 256 + tid;
        if (tid < 64) lh[tid] = 0;
        __syncthreads();
        int deg = 0, rank = 0;
        bool valid = (i < N_NODES);
        if (valid) {
            deg = row_ptr[i + 1] - row_ptr[i];
            if (deg > 63) deg = 63;
            rank = atomicAdd(&lh[deg], 1);          // LDS atomic: cheap
        }
        __syncthreads();
        if (tid < 64 && lh[tid] > 0)
            lbase[tid] = atomicAdd(&dcur[tid], lh[tid]);   // one global atomic per bin
        __syncthreads();
        if (valid) perm[dhoff[deg] + lbase[deg] + rank] = i;
    }
}

// ============ fused aggregate-first layer: Hout = bf16(relu(Agg(Hin) @ W + b)) ============
// TN=32, TWO-NODE SOFTWARE PIPELINE (r5 lesson: gather is latency-exposed, not BW-bound):
// both self-rows issued first; both edge lists staged; then two 8-row buffers (A=node0,
// B=node1) alternate issue/consume so one batch's loads are always in flight under the
// other's FMAs. Per-node FMA order (self, edges ascending) identical to prior version.
#define TN 32
#define GP2 136
#define CAPG 32

__device__ __forceinline__ void issue8(uint4* buf, const uint2* eRow, int dc, int abase,
                                       int c, const unsigned short* __restrict__ Hin, int sub) {
    #pragma unroll
    for (int j = 0; j < 8; ++j) {
        int e = c + j;
        int sj = (e < dc) ? (int)eRow[e].x : abase;
        buf[j] = ((const uint4*)(Hin + (size_t)sj * F))[sub];
    }
}
__device__ __forceinline__ void fma8(const uint4* buf, const uint2* eRow, int dc, float dd,
                                     int c, float4& aL, float4& aH) {
    #pragma unroll
    for (int j = 0; j < 8; ++j) {
        int e = c + j;
        float wj = (e < dc) ? __uint_as_float(eRow[e].y) * dd : 0.f;
        aL.x = fmaf(BF_LO(buf[j].x), wj, aL.x);
        aL.y = fmaf(BF_HI(buf[j].x), wj, aL.y);
        aL.z = fmaf(BF_LO(buf[j].y), wj, aL.z);
        aL.w = fmaf(BF_HI(buf[j].y), wj, aL.w);
        aH.x = fmaf(BF_LO(buf[j].z), wj, aH.x);
        aH.y = fmaf(BF_HI(buf[j].z), wj, aH.y);
        aH.z = fmaf(BF_LO(buf[j].w), wj, aH.z);
        aH.w = fmaf(BF_HI(buf[j].w), wj, aH.w);
    }
}

__global__ __launch_bounds__(256) void k_fused(const int* __restrict__ row_ptr,
                                               const int* __restrict__ esrc,
                                               const float* __restrict__ dinv,
                                               const int* __restrict__ perm,
                                               const unsigned short* __restrict__ Hin,
                                               const uint4* __restrict__ Whi,
                                               const uint4* __restrict__ Wlo,
                                               const float* __restrict__ bias,
                                               unsigned short* __restrict__ Hout, int n) {
    __shared__ unsigned short Gb[TN * GP2];   // 8.5 KB
    __shared__ uint2 eLg[TN][CAPG];           // 8 KB
    __shared__ int nodeL[TN], begL[TN], endL[TN];
    __shared__ float ddl[TN];
    int tid = threadIdx.x;
    int d0 = blockIdx.x * TN;
    int grp = tid >> 4, sub = tid & 15;

    if (tid < TN) {
        int slot = d0 + tid;
        int node = (slot < n) ? perm[slot] : -1;
        nodeL[tid] = node;
        if (node >= 0) {
            begL[tid] = row_ptr[node];
            endL[tid] = row_ptr[node + 1];
            ddl[tid] = dinv[node];
        } else {
            begL[tid] = 0; endL[tid] = 0; ddl[tid] = 0.f;
        }
    }
    __syncthreads();

    // ---- phase 1: two-node pipelined aggregation ----
    {
        int gi0 = grp, gi1 = grp + 16;
        int node0 = nodeL[gi0], node1 = nodeL[gi1];
        int beg0 = begL[gi0], deg0 = endL[gi0] - beg0;
        int beg1 = begL[gi1], deg1 = endL[gi1] - beg1;
        float dd0 = ddl[gi0], dd1 = ddl[gi1];
        int a0 = node0 >= 0 ? node0 : 0;
        int a1 = node1 >= 0 ? node1 : 0;

        // self rows: independent, issue first
        uint4 s0 = ((const uint4*)(Hin + (size_t)a0 * F))[sub];
        uint4 s1 = ((const uint4*)(Hin + (size_t)a1 * F))[sub];

        // stage both edge lists (src + dinv[src]) into LDS
        int dc0 = deg0 < CAPG ? deg0 : CAPG;
        int dc1 = deg1 < CAPG ? deg1 : CAPG;
        for (int i = sub; i < dc0; i += 16) {
            int s = esrc[beg0 + i];
            eLg[gi0][i] = make_uint2((unsigned)s, (unsigned)__float_as_int(dinv[s]));
        }
        for (int i = sub; i < dc1; i += 16) {
            int s = esrc[beg1 + i];
            eLg[gi1][i] = make_uint2((unsigned)s, (unsigned)__float_as_int(dinv[s]));
        }
        const uint2* eR0 = &eLg[gi0][0];
        const uint2* eR1 = &eLg[gi1][0];

        int nb0 = (dc0 + 7) >> 3, nb1 = (dc1 + 7) >> 3;   // 0..4 each
        uint4 bufA[8], bufB[8];
        if (nb0) issue8(bufA, eR0, dc0, a0, 0, Hin, sub);
        if (nb1) issue8(bufB, eR1, dc1, a1, 0, Hin, sub);

        float ws0 = node0 >= 0 ? dd0 * dd0 : 0.f;
        float ws1 = node1 >= 0 ? dd1 * dd1 : 0.f;
        float4 aL0, aH0, aL1, aH1;
        aL0.x = BF_LO(s0.x) * ws0; aL0.y = BF_HI(s0.x) * ws0;
        aL0.z = BF_LO(s0.y) * ws0; aL0.w = BF_HI(s0.y) * ws0;
        aH0.x = BF_LO(s0.z) * ws0; aH0.y = BF_HI(s0.z) * ws0;
        aH0.z = BF_LO(s0.w) * ws0; aH0.w = BF_HI(s0.w) * ws0;
        aL1.x = BF_LO(s1.x) * ws1; aL1.y = BF_HI(s1.x) * ws1;
        aL1.z = BF_LO(s1.y) * ws1; aL1.w = BF_HI(s1.y) * ws1;
        aH1.x = BF_LO(s1.z) * ws1; aH1.y = BF_HI(s1.z) * ws1;
        aH1.z = BF_LO(s1.w) * ws1; aH1.w = BF_HI(s1.w) * ws1;

        int nbm = nb0 > nb1 ? nb0 : nb1;
        #pragma unroll 1
        for (int t = 0; t < nbm; ++t) {
            if (t < nb0) {
                fma8(bufA, eR0, dc0, dd0, 8 * t, aL0, aH0);
                if (t + 1 < nb0) issue8(bufA, eR0, dc0, a0, 8 * (t + 1), Hin, sub);
            }
            if (t < nb1) {
                fma8(bufB, eR1, dc1, dd1, 8 * t, aL1, aH1);
                if (t + 1 < nb1) issue8(bufB, eR1, dc1, a1, 8 * (t + 1), Hin, sub);
            }
        }
        // rare overflow tail (deg > CAPG); P ~ 1e-7 per node
        for (int e = CAPG; e < deg0; ++e) {
            int sj = esrc[beg0 + e];
            float wj = dinv[sj] * dd0;
            uint4 r = ((const uint4*)(Hin + (size_t)sj * F))[sub];
            aL0.x = fmaf(BF_LO(r.x), wj, aL0.x); aL0.y = fmaf(BF_HI(r.x), wj, aL0.y);
            aL0.z = fmaf(BF_LO(r.y), wj, aL0.z); aL0.w = fmaf(BF_HI(r.y), wj, aL0.w);
            aH0.x = fmaf(BF_LO(r.z), wj, aH0.x); aH0.y = fmaf(BF_HI(r.z), wj, aH0.y);
            aH0.z = fmaf(BF_LO(r.w), wj, aH0.z); aH0.w = fmaf(BF_HI(r.w), wj, aH0.w);
        }
        for (int e = CAPG; e < deg1; ++e) {
            int sj = esrc[beg1 + e];
            float wj = dinv[sj] * dd1;
            uint4 r = ((const uint4*)(Hin + (size_t)sj * F))[sub];
            aL1.x = fmaf(BF_LO(r.x), wj, aL1.x); aL1.y = fmaf(BF_HI(r.x), wj, aL1.y);
            aL1.z = fmaf(BF_LO(r.y), wj, aL1.z); aL1.w = fmaf(BF_HI(r.y), wj, aL1.w);
            aH1.x = fmaf(BF_LO(r.z), wj, aH1.x); aH1.y = fmaf(BF_HI(r.z), wj, aH1.y);
            aH1.z = fmaf(BF_LO(r.w), wj, aH1.z); aH1.w = fmaf(BF_HI(r.w), wj, aH1.w);
        }

        uint4 o0, o1;
        o0.x = pk_bf16(aL0.x, aL0.y); o0.y = pk_bf16(aL0.z, aL0.w);
        o0.z = pk_bf16(aH0.x, aH0.y); o0.w = pk_bf16(aH0.z, aH0.w);
        o1.x = pk_bf16(aL1.x, aL1.y); o1.y = pk_bf16(aL1.z, aL1.w);
        o1.z = pk_bf16(aH1.x, aH1.y); o1.w = pk_bf16(aH1.z, aH1.w);
        *(uint4*)&Gb[gi0 * GP2 + 8 * sub] = o0;
        *(uint4*)&Gb[gi1 * GP2 + 8 * sub] = o1;
    }
    __syncthreads();

    // ---- phase 2: MFMA, each W fragment reused for both 16-row A-tiles ----
    int wave = tid >> 6, lane = tid & 63;
    int q = lane >> 4, m = lane & 15;
    f32x4 acc0[2], acc1[2];
    acc0[0] = (f32x4){0.f, 0.f, 0.f, 0.f};
    acc0[1] = (f32x4){0.f, 0.f, 0.f, 0.f};
    acc1[0] = (f32x4){0.f, 0.f, 0.f, 0.f};
    acc1[1] = (f32x4){0.f, 0.f, 0.f, 0.f};
    #pragma unroll
    for (int s = 0; s < 4; ++s) {
        U4H8 a0, a1;
        a0.u = *(const uint4*)&Gb[m * GP2 + 32 * s + 8 * q];
        a1.u = *(const uint4*)&Gb[(m + 16) * GP2 + 32 * s + 8 * q];
        #pragma unroll
        for (int cc = 0; cc < 2; ++cc) {
            int c = wave * 2 + cc;
            U4H8 bh, bl;
            bh.u = Whi[(s * 8 + c) * 64 + lane];
            bl.u = Wlo[(s * 8 + c) * 64 + lane];
            acc0[cc] = __builtin_amdgcn_mfma_f32_16x16x32_bf16(a0.h, bh.h, acc0[cc], 0, 0, 0);
            acc0[cc] = __builtin_amdgcn_mfma_f32_16x16x32_bf16(a0.h, bl.h, acc0[cc], 0, 0, 0);
            acc1[cc] = __builtin_amdgcn_mfma_f32_16x16x32_bf16(a1.h, bh.h, acc1[cc], 0, 0, 0);
            acc1[cc] = __builtin_amdgcn_mfma_f32_16x16x32_bf16(a1.h, bl.h, acc1[cc], 0, 0, 0);
        }
    }
    __syncthreads();

    // ---- epilogue ----
    #pragma unroll
    for (int cc = 0; cc < 2; ++cc) {
        int c = wave * 2 + cc;
        float bb = bias[16 * c + m];
        #pragma unroll
        for (int r = 0; r < 4; ++r) {
            Gb[(4 * q + r) * GP2 + 16 * c + m] = bf16_1(fmaxf(acc0[cc][r] + bb, 0.f));
            Gb[(16 + 4 * q + r) * GP2 + 16 * c + m] = bf16_1(fmaxf(acc1[cc][r] + bb, 0.f));
        }
    }
    __syncthreads();
    {
        int row = tid >> 4, c8 = tid & 15;
        #pragma unroll
        for (int rr = 0; rr < 2; ++rr) {
            int r2 = row + 16 * rr;
            int onode = nodeL[r2];
            if (onode >= 0) {
                uint4 o = *(const uint4*)&Gb[r2 * GP2 + c8 * 8];
                ((uint4*)(Hout + (size_t)onode * F))[c8] = o;
            }
        }
    }
}

// ============ fused pool (segment mean via precomputed bounds) + FC head ============
__global__ __launch_bounds__(256) void k_pool_fc(const unsigned short* __restrict__ Hb,
                                                 const int* __restrict__ gs,
                                                 const float* __restrict__ Wf1,
                                                 const float* __restrict__ bf1,
                                                 const float* __restrict__ Wf2,
                                                 const float* __restrict__ bf2,
                                                 float* __restrict__ out) {
    int g = blockIdx.x;
    int tid = threadIdx.x;
    int start = gs[g], end = gs[g + 1];

    __shared__ float hs[4][F];
    __shared__ float hg[F];
    int wv = tid >> 6, lane = tid & 63;
    int half = lane >> 5, sub = lane & 31;
    float4 a = make_float4(0.f, 0.f, 0.f, 0.f);
    for (int i = start + wv * 2 + half; i < end; i += 8) {
        uint2 v = ((const uint2*)(Hb + (size_t)i * F))[sub];
        a.x += BF_LO(v.x); a.y += BF_HI(v.x);
        a.z += BF_LO(v.y); a.w += BF_HI(v.y);
    }
    a.x += __shfl_xor(a.x, 32, 64);
    a.y += __shfl_xor(a.y, 32, 64);
    a.z += __shfl_xor(a.z, 32, 64);
    a.w += __shfl_xor(a.w, 32, 64);
    if (half == 0) ((float4*)hs[wv])[sub] = a;
    __syncthreads();
    if (tid < F) {
        float inv = 1.0f / (float)((end - start) > 0 ? (end - start) : 1);
        hg[tid] = (hs[0][tid] + hs[1][tid] + hs[2][tid] + hs[3][tid]) * inv;
    }
    __syncthreads();
    if (tid < 64) {
        float acc = bf1[tid];
        #pragma unroll 4
        for (int f = 0; f < F; ++f) acc = fmaf(hg[f], Wf1[f * 64 + tid], acc);
        float v = fmaxf(acc, 0.f) * Wf2[tid];
        #pragma unroll
        for (int off = 32; off > 0; off >>= 1) v += __shfl_down(v, off, 64);
        if (tid == 0) out[g] = v + bf2[0];
    }
}

extern "C" void kernel_launch(void* const* d_in, const int* in_sizes, int n_in,
                              void* d_out, int out_size, void* d_ws, size_t ws_size,
                              hipStream_t stream) {
    const float* x    = (const float*)d_in[0];
    const int* eidx   = (const int*)d_in[1];
    const int* batch  = (const int*)d_in[2];
    const float* W1   = (const float*)d_in[3];
    const float* b1   = (const float*)d_in[4];
    const float* W2   = (const float*)d_in[5];
    const float* b2   = (const float*)d_in[6];
    const float* W3   = (const float*)d_in[7];
    const float* b3   = (const float*)d_in[8];
    const float* Wf1  = (const float*)d_in[9];
    const float* bf1  = (const float*)d_in[10];
    const float* Wf2  = (const float*)d_in[11];
    const float* bf2  = (const float*)d_in[12];
    float* out = (float*)d_out;

    const int* src = eidx;
    const int* dst = eidx + N_EDGES;

    char* p = (char*)d_ws;
    unsigned short* Xb  = (unsigned short*)p;  p += (size_t)N_NODES * F * 2;
    unsigned short* H1  = (unsigned short*)p;  p += (size_t)N_NODES * F * 2;
    unsigned short* H2  = (unsigned short*)p;  p += (size_t)N_NODES * F * 2;
    unsigned short* H3  = (unsigned short*)p;  p += (size_t)N_NODES * F * 2;
    int* esrc   = (int*)p;     p += (size_t)N_EDGES * sizeof(int);
    int* rnk    = (int*)p;     p += (size_t)N_EDGES * sizeof(int);
    uint4* Whi  = (uint4*)p;   p += (size_t)3 * 2048 * sizeof(uint4);
    uint4* Wlo  = (uint4*)p;   p += (size_t)3 * 2048 * sizeof(uint4);
    float* dinv = (float*)p;   p += (size_t)N_NODES * sizeof(float);
    int* cnt     = (int*)p;    p += (size_t)N_NODES * sizeof(int);
    int* dh      = (int*)p;    p += 64 * sizeof(int);          // zeroed with cnt (adjacent)
    int* row_ptr = (int*)p;    p += (size_t)(N_NODES + 1) * sizeof(int);
    int* blksums = (int*)p;    p += 256 * sizeof(int);
    int* gs      = (int*)p;    p += (size_t)(N_GRAPHS + 1) * sizeof(int);
    int* dhoff   = (int*)p;    p += 64 * sizeof(int);
    int* dcur    = (int*)p;    p += 64 * sizeof(int);
    int* perm    = (int*)p;    p += (size_t)N_NODES * sizeof(int);

    dim3 b256(256);
    int gNodes = (N_NODES + 255) / 256;           // 196
    int gFused = (N_NODES + TN - 1) / TN;         // 1563

    // ---- prep (cvt + hist/rank + prepW + pool bounds); cnt+dh zeroed first ----
    hipMemsetAsync(cnt, 0, ((size_t)N_NODES + 64) * sizeof(int), stream);
    k_prep<<<G_CVT + G_HIST + G_PREPW + G_BND, b256, 0, stream>>>(x, Xb, dst, cnt, rnk, W1, W2, W3,
                                                                  Whi, Wlo, batch, gs);

    // ---- CSR scan + atomic-free fill + degree-sort placement ----
    k_scan1<<<gNodes, b256, 0, stream>>>(cnt, row_ptr, blksums, dinv, dh, N_NODES);
    k_scan23<<<gNodes, b256, 0, stream>>>(row_ptr, blksums, dh, dhoff, dcur, N_NODES, N_EDGES);
    k_fill<<<G_FILL + G_PLACE, b256, 0, stream>>>(src, dst, row_ptr, rnk, esrc,
                                                  dhoff, dcur, perm, N_EDGES);

    // ---- 3 aggregate-first fused layers (degree-sorted, TN=32, pipelined gather) ----
    k_fused<<<gFused, b256, 0, stream>>>(row_ptr, esrc, dinv, perm, Xb, Whi,        Wlo,        b1, H1, N_NODES);
    k_fused<<<gFused, b256, 0, stream>>>(row_ptr, esrc, dinv, perm, H1, Whi + 2048, Wlo + 2048, b2, H2, N_NODES);
    k_fused<<<gFused, b256, 0, stream>>>(row_ptr, esrc, dinv, perm, H2, Whi + 4096, Wlo + 4096, b3, H3, N_NODES);

    // ---- pool + FC ----
    k_pool_fc<<<N_GRAPHS, b256, 0, stream>>>(H3, gs, Wf1, bf1, Wf2, bf2, out);
}

// Round 7
// 243.319 us; speedup vs baseline: 1.0891x; 1.0891x over previous
//
#include <hip/hip_runtime.h>

#define N_NODES 50000
#define N_EDGES 600000
#define N_GRAPHS 500
#define F 128

typedef short bf16x8 __attribute__((ext_vector_type(8)));
typedef float f32x4 __attribute__((ext_vector_type(4)));
union U4H8 { uint4 u; bf16x8 h; };

// ---- bf16 helpers (RNE) ----
__device__ inline unsigned pk_bf16(float a, float b) {
    unsigned ua = __float_as_uint(a), ub = __float_as_uint(b);
    ua = (ua + 0x7fffu + ((ua >> 16) & 1u)) >> 16;
    ub = (ub + 0x7fffu + ((ub >> 16) & 1u)) >> 16;
    return ua | (ub << 16);
}
__device__ inline float bf16_rnd(float x) {
    unsigned u = __float_as_uint(x);
    u = (u + 0x7fffu + ((u >> 16) & 1u)) & 0xffff0000u;
    return __uint_as_float(u);
}
__device__ inline unsigned short bf16_1(float a) {
    unsigned ua = __float_as_uint(a);
    return (unsigned short)((ua + 0x7fffu + ((ua >> 16) & 1u)) >> 16);
}
#define BF_LO(u) __uint_as_float((u) << 16)
#define BF_HI(u) __uint_as_float((u) & 0xffff0000u)

#define G_CVT  3125
#define G_HIST 2344
#define G_PREPW 24
#define G_BND  196

// ====== merged prep: x->bf16 | 8-REPLICA dst histogram (saves per-copy rank) | W split-pack
// | pool bounds. r6 lesson: single-copy hist = ~35us of same-address atomic serialization
// (12 RMWs/counter avg); 8 replicas (copy = (e>>8)&7, XCD-aligned under round-robin) cut
// per-address chains ~8x. Global rank = rnk[e] + cross-copy exclusive offset (scan1).
__global__ __launch_bounds__(256) void k_prep(const float* __restrict__ x, unsigned short* __restrict__ xb,
                                              const int* __restrict__ dst, int* __restrict__ cnt8,
                                              int* __restrict__ rnk,
                                              const float* __restrict__ W1, const float* __restrict__ W2,
                                              const float* __restrict__ W3,
                                              uint4* __restrict__ Whi, uint4* __restrict__ Wlo,
                                              const int* __restrict__ batch, int* __restrict__ gs) {
    int b = blockIdx.x, tid = threadIdx.x;
    if (b < G_CVT) {
        int idx = b * 256 + tid;
        if (idx < N_NODES * F / 8) {
            const float4* xr = (const float4*)(x + (size_t)idx * 8);
            float4 a = xr[0], c = xr[1];
            uint4 o;
            o.x = pk_bf16(a.x, a.y); o.y = pk_bf16(a.z, a.w);
            o.z = pk_bf16(c.x, c.y); o.w = pk_bf16(c.z, c.w);
            ((uint4*)xb)[idx] = o;
        }
    } else if (b < G_CVT + G_HIST) {
        int e = (b - G_CVT) * 256 + tid;
        if (e < N_EDGES) {
            int c = ((unsigned)e >> 8) & 7;
            rnk[e] = atomicAdd(&cnt8[c * N_NODES + dst[e]], 1);
        }
    } else if (b < G_CVT + G_HIST + G_PREPW) {
        int idx = (b - G_CVT - G_HIST) * 256 + tid;   // 0..6143
        int layer = idx >> 11;
        const float* W = (layer == 0) ? W1 : (layer == 1) ? W2 : W3;
        int t = idx & 2047;
        int lane = t & 63, sc = t >> 6;
        int s = sc >> 3, c = sc & 7;
        int q = lane >> 4, m = lane & 15;
        int k0 = 32 * s + 8 * q, n0 = 16 * c + m;
        float w[8], h[8];
        #pragma unroll
        for (int j = 0; j < 8; ++j) {
            w[j] = W[(k0 + j) * F + n0];
            h[j] = bf16_rnd(w[j]);
        }
        uint4 uh, ul;
        uh.x = pk_bf16(h[0], h[1]); uh.y = pk_bf16(h[2], h[3]);
        uh.z = pk_bf16(h[4], h[5]); uh.w = pk_bf16(h[6], h[7]);
        ul.x = pk_bf16(w[0] - h[0], w[1] - h[1]); ul.y = pk_bf16(w[2] - h[2], w[3] - h[3]);
        ul.z = pk_bf16(w[4] - h[4], w[5] - h[5]); ul.w = pk_bf16(w[6] - h[6], w[7] - h[7]);
        Whi[idx] = uh;
        Wlo[idx] = ul;
    } else {
        int i = (b - G_CVT - G_HIST - G_PREPW) * 256 + tid;
        if (i < N_NODES) {
            int bi = batch[i];
            if (i == 0) {
                for (int g = 0; g <= bi; ++g) gs[g] = 0;
            } else {
                int bp = batch[i - 1];
                for (int g = bp + 1; g <= bi; ++g) gs[g] = i;
            }
            if (i == N_NODES - 1) {
                for (int g = bi + 1; g <= N_GRAPHS; ++g) gs[g] = N_NODES;
            }
        }
    }
}

// ================= CSR scan + fill + degree-sort =================
// scan1: sums the 8 hist replicas (v = total degree) and REWRITES cnt8 in place with the
// cross-copy exclusive prefix, so k_fill's slot = row_ptr[d] + cnt8[c][d] + rnk[e].
__global__ __launch_bounds__(256) void k_scan1(int* __restrict__ cnt8, int* __restrict__ row_ptr,
                                               int* __restrict__ blksums, float* __restrict__ dinv,
                                               int* __restrict__ dh, int n) {
    __shared__ int s[256];
    __shared__ int dhl[64];
    int tid = threadIdx.x;
    int i = blockIdx.x * 256 + tid;
    if (tid < 64) dhl[tid] = 0;
    int v = 0;
    if (i < n) {
        int pc[8];
        #pragma unroll
        for (int c = 0; c < 8; ++c) pc[c] = cnt8[c * n + i];
        #pragma unroll
        for (int c = 0; c < 8; ++c) { int t = pc[c]; pc[c] = v; v += t; }
        #pragma unroll
        for (int c = 0; c < 8; ++c) cnt8[c * n + i] = pc[c];
        dinv[i] = rsqrtf((float)(v + 1));
    }
    s[tid] = v;
    __syncthreads();
    if (i < n) atomicAdd(&dhl[v < 63 ? v : 63], 1);
    for (int off = 1; off < 256; off <<= 1) {
        int t = (tid >= off) ? s[tid - off] : 0;
        __syncthreads();
        s[tid] += t;
        __syncthreads();
    }
    if (i < n) row_ptr[i] = s[tid] - v;
    if (tid == 255) blksums[blockIdx.x] = s[255];
    __syncthreads();
    if (tid < 64 && dhl[tid] > 0) atomicAdd(&dh[tid], dhl[tid]);
}

__global__ __launch_bounds__(256) void k_scan23(int* __restrict__ row_ptr, const int* __restrict__ blksums,
                                                const int* __restrict__ dh, int* __restrict__ dhoff,
                                                int* __restrict__ dcur, int n, int ne) {
    __shared__ int s[256];
    int tid = threadIdx.x;
    s[tid] = (tid < (int)blockIdx.x) ? blksums[tid] : 0;
    __syncthreads();
    for (int off = 128; off > 0; off >>= 1) {
        if (tid < off) s[tid] += s[tid + off];
        __syncthreads();
    }
    int base = s[0];
    int i = blockIdx.x * 256 + tid;
    if (i < n) row_ptr[i] += base;
    if (i == 0) row_ptr[n] = ne;
    if (blockIdx.x == 0 && tid < 64) {
        int v = dh[tid];
        int x = v;
        #pragma unroll
        for (int off = 1; off < 64; off <<= 1) {
            int t = __shfl_up(x, off, 64);
            if (tid >= off) x += t;
        }
        dhoff[tid] = x - v;   // exclusive prefix
        dcur[tid] = 0;
    }
}

#define G_FILL 2344
#define G_PLACE 196
// fill: ATOMIC-FREE CSR scatter (pos = row_ptr[dst] + copy-offset + saved per-copy rank);
// placement: block-aggregated degree-sort (one global atomic per (block,bin))
__global__ __launch_bounds__(256) void k_fill(const int* __restrict__ src, const int* __restrict__ dst,
                                              const int* __restrict__ row_ptr, const int* __restrict__ rnk,
                                              const int* __restrict__ cnt8,
                                              int* __restrict__ esrc,
                                              const int* __restrict__ dhoff, int* __restrict__ dcur,
                                              int* __restrict__ perm, int ne) {
    __shared__ int lh[64];
    __shared__ int lbase[64];
    int b = blockIdx.x, tid = threadIdx.x;
    if (b < G_FILL) {
        int e = b * 256 + tid;
        if (e < ne) {
            int d = dst[e];
            int c = ((unsigned)e >> 8) & 7;
            esrc[row_ptr[d] + cnt8[c * N_NODES + d] + rnk[e]] = src[e];
        }
    } else {
        int i = (b - G_FILL) * 256 + tid;
        if (tid < 64) lh[tid] = 0;
        __syncthreads();
        int deg = 0, rank = 0;
        bool valid = (i < N_NODES);
        if (valid) {
            deg = row_ptr[i + 1] - row_ptr[i];
            if (deg > 63) deg = 63;
            rank = atomicAdd(&lh[deg], 1);          // LDS atomic: cheap
        }
        __syncthreads();
        if (tid < 64 && lh[tid] > 0)
            lbase[tid] = atomicAdd(&dcur[tid], lh[tid]);   // one global atomic per bin
        __syncthreads();
        if (valid) perm[dhoff[deg] + lbase[deg] + rank] = i;
    }
}

// ============ fused aggregate-first layer: Hout = bf16(relu(Agg(Hin) @ W + b)) ============
// TN=32 node tile (R5 version — r6's two-buffer ILP pipeline cost 64 VGPRs and regressed
// via an occupancy cliff; TLP was already hiding the gather latency). Edge records are
// src-only (4B); dinv[src] looked up at staging time from the L2-hot table.
#define TN 32
#define GP2 136
#define CAPG 32
__global__ __launch_bounds__(256) void k_fused(const int* __restrict__ row_ptr,
                                               const int* __restrict__ esrc,
                                               const float* __restrict__ dinv,
                                               const int* __restrict__ perm,
                                               const unsigned short* __restrict__ Hin,
                                               const uint4* __restrict__ Whi,
                                               const uint4* __restrict__ Wlo,
                                               const float* __restrict__ bias,
                                               unsigned short* __restrict__ Hout, int n) {
    __shared__ unsigned short Gb[TN * GP2];   // 8.5 KB
    __shared__ uint2 eLg[TN][CAPG];           // 8 KB
    __shared__ int nodeL[TN], begL[TN], endL[TN];
    __shared__ float ddl[TN];
    int tid = threadIdx.x;
    int d0 = blockIdx.x * TN;
    int grp = tid >> 4, sub = tid & 15;

    if (tid < TN) {
        int slot = d0 + tid;
        int node = (slot < n) ? perm[slot] : -1;
        nodeL[tid] = node;
        if (node >= 0) {
            begL[tid] = row_ptr[node];
            endL[tid] = row_ptr[node + 1];
            ddl[tid] = dinv[node];
        } else {
            begL[tid] = 0; endL[tid] = 0; ddl[tid] = 0.f;
        }
    }
    __syncthreads();

    // ---- phase 1: aggregate two nodes per 16-lane group (rows gi, gi+16) ----
    #pragma unroll 1
    for (int n2 = 0; n2 < 2; ++n2) {
        int gi = grp + 16 * n2;
        int node = nodeL[gi];
        int beg = begL[gi], end = endL[gi];
        int deg = end - beg;
        float dd = ddl[gi];

        int degc = deg < CAPG ? deg : CAPG;
        for (int i = sub; i < degc; i += 16) {
            int s = esrc[beg + i];
            eLg[gi][i] = make_uint2((unsigned)s, (unsigned)__float_as_int(dinv[s]));
        }

        float4 accL = make_float4(0.f, 0.f, 0.f, 0.f);
        float4 accH = make_float4(0.f, 0.f, 0.f, 0.f);
        if (node >= 0) {
            uint4 srow = ((const uint4*)(Hin + (size_t)node * F))[sub];
            float ws = dd * dd;
            accL.x = BF_LO(srow.x) * ws;
            accL.y = BF_HI(srow.x) * ws;
            accL.z = BF_LO(srow.y) * ws;
            accL.w = BF_HI(srow.y) * ws;
            accH.x = BF_LO(srow.z) * ws;
            accH.y = BF_HI(srow.z) * ws;
            accH.z = BF_LO(srow.w) * ws;
            accH.w = BF_HI(srow.w) * ws;
            for (int c = 0; c < deg; c += 8) {
                int sjs[8];
                #pragma unroll
                for (int j = 0; j < 8; ++j) {
                    int e = c + j;
                    int sj = node;
                    if (e < deg) sj = (e < CAPG) ? (int)eLg[gi][e].x
                                                 : esrc[beg + e];
                    sjs[j] = sj;
                }
                uint4 rows[8];
                #pragma unroll
                for (int j = 0; j < 8; ++j)
                    rows[j] = ((const uint4*)(Hin + (size_t)sjs[j] * F))[sub];
                #pragma unroll
                for (int j = 0; j < 8; ++j) {
                    int e = c + j;
                    float wj = 0.f;
                    if (e < deg) {
                        float dv = (e < CAPG) ? __uint_as_float(eLg[gi][e].y)
                                              : dinv[sjs[j]];
                        wj = dv * dd;
                    }
                    accL.x = fmaf(BF_LO(rows[j].x), wj, accL.x);
                    accL.y = fmaf(BF_HI(rows[j].x), wj, accL.y);
                    accL.z = fmaf(BF_LO(rows[j].y), wj, accL.z);
                    accL.w = fmaf(BF_HI(rows[j].y), wj, accL.w);
                    accH.x = fmaf(BF_LO(rows[j].z), wj, accH.x);
                    accH.y = fmaf(BF_HI(rows[j].z), wj, accH.y);
                    accH.z = fmaf(BF_LO(rows[j].w), wj, accH.z);
                    accH.w = fmaf(BF_HI(rows[j].w), wj, accH.w);
                }
            }
        }
        {
            uint4 o;
            o.x = pk_bf16(accL.x, accL.y);
            o.y = pk_bf16(accL.z, accL.w);
            o.z = pk_bf16(accH.x, accH.y);
            o.w = pk_bf16(accH.z, accH.w);
            *(uint4*)&Gb[gi * GP2 + 8 * sub] = o;
        }
    }
    __syncthreads();

    // ---- phase 2: MFMA, each W fragment reused for both 16-row A-tiles ----
    int wave = tid >> 6, lane = tid & 63;
    int q = lane >> 4, m = lane & 15;
    f32x4 acc0[2], acc1[2];
    acc0[0] = (f32x4){0.f, 0.f, 0.f, 0.f};
    acc0[1] = (f32x4){0.f, 0.f, 0.f, 0.f};
    acc1[0] = (f32x4){0.f, 0.f, 0.f, 0.f};
    acc1[1] = (f32x4){0.f, 0.f, 0.f, 0.f};
    #pragma unroll
    for (int s = 0; s < 4; ++s) {
        U4H8 a0, a1;
        a0.u = *(const uint4*)&Gb[m * GP2 + 32 * s + 8 * q];
        a1.u = *(const uint4*)&Gb[(m + 16) * GP2 + 32 * s + 8 * q];
        #pragma unroll
        for (int cc = 0; cc < 2; ++cc) {
            int c = wave * 2 + cc;
            U4H8 bh, bl;
            bh.u = Whi[(s * 8 + c) * 64 + lane];
            bl.u = Wlo[(s * 8 + c) * 64 + lane];
            acc0[cc] = __builtin_amdgcn_mfma_f32_16x16x32_bf16(a0.h, bh.h, acc0[cc], 0, 0, 0);
            acc0[cc] = __builtin_amdgcn_mfma_f32_16x16x32_bf16(a0.h, bl.h, acc0[cc], 0, 0, 0);
            acc1[cc] = __builtin_amdgcn_mfma_f32_16x16x32_bf16(a1.h, bh.h, acc1[cc], 0, 0, 0);
            acc1[cc] = __builtin_amdgcn_mfma_f32_16x16x32_bf16(a1.h, bl.h, acc1[cc], 0, 0, 0);
        }
    }
    __syncthreads();

    // ---- epilogue ----
    #pragma unroll
    for (int cc = 0; cc < 2; ++cc) {
        int c = wave * 2 + cc;
        float bb = bias[16 * c + m];
        #pragma unroll
        for (int r = 0; r < 4; ++r) {
            Gb[(4 * q + r) * GP2 + 16 * c + m] = bf16_1(fmaxf(acc0[cc][r] + bb, 0.f));
            Gb[(16 + 4 * q + r) * GP2 + 16 * c + m] = bf16_1(fmaxf(acc1[cc][r] + bb, 0.f));
        }
    }
    __syncthreads();
    {
        int row = tid >> 4, c8 = tid & 15;
        #pragma unroll
        for (int rr = 0; rr < 2; ++rr) {
            int r2 = row + 16 * rr;
            int onode = nodeL[r2];
            if (onode >= 0) {
                uint4 o = *(const uint4*)&Gb[r2 * GP2 + c8 * 8];
                ((uint4*)(Hout + (size_t)onode * F))[c8] = o;
            }
        }
    }
}

// ============ fused pool (segment mean via precomputed bounds) + FC head ============
__global__ __launch_bounds__(256) void k_pool_fc(const unsigned short* __restrict__ Hb,
                                                 const int* __restrict__ gs,
                                                 const float* __restrict__ Wf1,
                                                 const float* __restrict__ bf1,
                                                 const float* __restrict__ Wf2,
                                                 const float* __restrict__ bf2,
                                                 float* __restrict__ out) {
    int g = blockIdx.x;
    int tid = threadIdx.x;
    int start = gs[g], end = gs[g + 1];

    __shared__ float hs[4][F];
    __shared__ float hg[F];
    int wv = tid >> 6, lane = tid & 63;
    int half = lane >> 5, sub = lane & 31;
    float4 a = make_float4(0.f, 0.f, 0.f, 0.f);
    for (int i = start + wv * 2 + half; i < end; i += 8) {
        uint2 v = ((const uint2*)(Hb + (size_t)i * F))[sub];
        a.x += BF_LO(v.x); a.y += BF_HI(v.x);
        a.z += BF_LO(v.y); a.w += BF_HI(v.y);
    }
    a.x += __shfl_xor(a.x, 32, 64);
    a.y += __shfl_xor(a.y, 32, 64);
    a.z += __shfl_xor(a.z, 32, 64);
    a.w += __shfl_xor(a.w, 32, 64);
    if (half == 0) ((float4*)hs[wv])[sub] = a;
    __syncthreads();
    if (tid < F) {
        float inv = 1.0f / (float)((end - start) > 0 ? (end - start) : 1);
        hg[tid] = (hs[0][tid] + hs[1][tid] + hs[2][tid] + hs[3][tid]) * inv;
    }
    __syncthreads();
    if (tid < 64) {
        float acc = bf1[tid];
        #pragma unroll 4
        for (int f = 0; f < F; ++f) acc = fmaf(hg[f], Wf1[f * 64 + tid], acc);
        float v = fmaxf(acc, 0.f) * Wf2[tid];
        #pragma unroll
        for (int off = 32; off > 0; off >>= 1) v += __shfl_down(v, off, 64);
        if (tid == 0) out[g] = v + bf2[0];
    }
}

extern "C" void kernel_launch(void* const* d_in, const int* in_sizes, int n_in,
                              void* d_out, int out_size, void* d_ws, size_t ws_size,
                              hipStream_t stream) {
    const float* x    = (const float*)d_in[0];
    const int* eidx   = (const int*)d_in[1];
    const int* batch  = (const int*)d_in[2];
    const float* W1   = (const float*)d_in[3];
    const float* b1   = (const float*)d_in[4];
    const float* W2   = (const float*)d_in[5];
    const float* b2   = (const float*)d_in[6];
    const float* W3   = (const float*)d_in[7];
    const float* b3   = (const float*)d_in[8];
    const float* Wf1  = (const float*)d_in[9];
    const float* bf1  = (const float*)d_in[10];
    const float* Wf2  = (const float*)d_in[11];
    const float* bf2  = (const float*)d_in[12];
    float* out = (float*)d_out;

    const int* src = eidx;
    const int* dst = eidx + N_EDGES;

    char* p = (char*)d_ws;
    unsigned short* Xb  = (unsigned short*)p;  p += (size_t)N_NODES * F * 2;
    unsigned short* H1  = (unsigned short*)p;  p += (size_t)N_NODES * F * 2;
    unsigned short* H2  = (unsigned short*)p;  p += (size_t)N_NODES * F * 2;
    unsigned short* H3  = (unsigned short*)p;  p += (size_t)N_NODES * F * 2;
    int* esrc   = (int*)p;     p += (size_t)N_EDGES * sizeof(int);
    int* rnk    = (int*)p;     p += (size_t)N_EDGES * sizeof(int);
    uint4* Whi  = (uint4*)p;   p += (size_t)3 * 2048 * sizeof(uint4);
    uint4* Wlo  = (uint4*)p;   p += (size_t)3 * 2048 * sizeof(uint4);
    float* dinv = (float*)p;   p += (size_t)N_NODES * sizeof(float);
    int* cnt8    = (int*)p;    p += (size_t)8 * N_NODES * sizeof(int);
    int* dh      = (int*)p;    p += 64 * sizeof(int);          // zeroed with cnt8 (adjacent)
    int* row_ptr = (int*)p;    p += (size_t)(N_NODES + 1) * sizeof(int);
    int* blksums = (int*)p;    p += 256 * sizeof(int);
    int* gs      = (int*)p;    p += (size_t)(N_GRAPHS + 1) * sizeof(int);
    int* dhoff   = (int*)p;    p += 64 * sizeof(int);
    int* dcur    = (int*)p;    p += 64 * sizeof(int);
    int* perm    = (int*)p;    p += (size_t)N_NODES * sizeof(int);

    dim3 b256(256);
    int gNodes = (N_NODES + 255) / 256;           // 196
    int gFused = (N_NODES + TN - 1) / TN;         // 1563

    // ---- prep (cvt + 8-replica hist/rank + prepW + pool bounds); cnt8+dh zeroed first ----
    hipMemsetAsync(cnt8, 0, ((size_t)8 * N_NODES + 64) * sizeof(int), stream);
    k_prep<<<G_CVT + G_HIST + G_PREPW + G_BND, b256, 0, stream>>>(x, Xb, dst, cnt8, rnk, W1, W2, W3,
                                                                  Whi, Wlo, batch, gs);

    // ---- CSR scan (sums replicas, writes copy-offsets in place) + atomic-free fill ----
    k_scan1<<<gNodes, b256, 0, stream>>>(cnt8, row_ptr, blksums, dinv, dh, N_NODES);
    k_scan23<<<gNodes, b256, 0, stream>>>(row_ptr, blksums, dh, dhoff, dcur, N_NODES, N_EDGES);
    k_fill<<<G_FILL + G_PLACE, b256, 0, stream>>>(src, dst, row_ptr, rnk, cnt8, esrc,
                                                  dhoff, dcur, perm, N_EDGES);

    // ---- 3 aggregate-first fused layers (degree-sorted, TN=32) ----
    k_fused<<<gFused, b256, 0, stream>>>(row_ptr, esrc, dinv, perm, Xb, Whi,        Wlo,        b1, H1, N_NODES);
    k_fused<<<gFused, b256, 0, stream>>>(row_ptr, esrc, dinv, perm, H1, Whi + 2048, Wlo + 2048, b2, H2, N_NODES);
    k_fused<<<gFused, b256, 0, stream>>>(row_ptr, esrc, dinv, perm, H2, Whi + 4096, Wlo + 4096, b3, H3, N_NODES);

    // ---- pool + FC ----
    k_pool_fc<<<N_GRAPHS, b256, 0, stream>>>(H3, gs, Wf1, bf1, Wf2, bf2, out);
}